// Round 15
// baseline (229.472 us; speedup 1.0000x reference)
//
#include <hip/hip_runtime.h>

// DenseFeatureNumericEmbedding: out[b, f*16+e] = sum_h relu(x[b,f]*W1[f,h]+b1[f,h])*W2[f,e,h] + b2[f,e]
// Piecewise-linear reformulation: per (f,e) the map x->emb is piecewise linear with
// breakpoints t_h = -b1/W1; tables hold slope/intercept per (f, interval, e).
//
// Ledger: R5a build (f,e)-parallel [-28us CONFIRMED]. Embed insensitive to: read
// path (LDS vs L2), grid order, nt flag, store geometry, vmcnt ordering, and
// (R14) write volume is charged at ~5.4TB/s MARGINAL (near fill rate) -> the
// write path has 3x headroom vs embed's own ~2.4TB/s effective. R14 also proved
// the timed window holds ~118us of harness ops (83+4+84 < 205), so embed ~55-60us.
// Cause of the remaining ~35us over BW floor: UNKNOWN after 6 falsifications, and
// embed's own counters have never been visible (top-5 always harness fills).
// R16 DIAGNOSTIC: force embed into the top-5 by tripling its write volume (2 dup
// regions in ws). Buys FETCH_SIZE/WRITE_SIZE/VALUBusy/Occupancy for the hot kernel.
//   Read grid: FETCH ~10-25MB -> latency/stall-bound, next raise occupancy;
//   FETCH >>100MB -> read amplification (L2 thrash), attack table caching;
//   WRITE >> 3x134MB -> store amplification, attack granularity.

#define F_   128
#define H_   64
#define E_   16
#define NROW 65            // intervals 0..64
#define GRS  32            // table row stride in floats (16 S + 16 T)
#define RPB  4             // batch rows per block
#define THREADS 256

typedef float vf4 __attribute__((ext_vector_type(4)));

// ---------------- build kernel: one wave per (feature, e) ----------------
__global__ __launch_bounds__(64) void build_tables(
    const float* __restrict__ W1, const float* __restrict__ B1,
    const float* __restrict__ W2, const float* __restrict__ B2,
    float* __restrict__ tbl, float* __restrict__ bps)
{
    const int f = blockIdx.x;   // 0..127
    const int e = blockIdx.y;   // 0..15
    const int h = threadIdx.x;  // 0..63

    __shared__ float ts_raw[H_];
    __shared__ float ts_sorted[H_];
    __shared__ float scS[H_];
    __shared__ float scT[H_];

    const float w1 = W1[f * H_ + h];
    const float bb = B1[f * H_ + h];
    const bool  slope = (w1 != 0.0f);
    const float t   = slope ? (-bb / w1) : __builtin_inff();
    const float sgn = slope ? (w1 > 0.0f ? 1.0f : -1.0f) : 0.0f;
    // active as x -> -inf: W1<0 terms (x*W1 -> +inf), plus constant-on terms (W1==0, b1>0)
    const bool act0 = (w1 < 0.0f) || (!slope && bb > 0.0f);

    ts_raw[h] = t;
    __syncthreads();
    int rank = 0;
    #pragma unroll
    for (int j = 0; j < H_; ++j) {
        float tj = ts_raw[j];
        rank += (tj < t || (tj == t && j < h)) ? 1 : 0;  // tie-break by index -> permutation
    }
    ts_sorted[rank] = t;
    __syncthreads();
    if (e == 0) bps[f * H_ + h] = ts_sorted[h];

    const float w2 = W2[(f * E_ + e) * H_ + h];
    // crossing t_h upward: W1>0 -> term turns ON (+), W1<0 -> OFF (-)
    const float dS = sgn * w1 * w2;
    const float dT = sgn * bb * w2;
    float bS = act0 ? w1 * w2 : 0.0f;
    float bT = act0 ? bb * w2 : 0.0f;
    #pragma unroll
    for (int d = 32; d; d >>= 1) { bS += __shfl_xor(bS, d); bT += __shfl_xor(bT, d); }

    scS[rank] = dS; scT[rank] = dT;  // scatter deltas into sorted order
    __syncthreads();
    float vS = scS[h], vT = scT[h];
    #pragma unroll
    for (int d = 1; d < 64; d <<= 1) {   // inclusive scan over sorted positions
        float uS = __shfl_up(vS, (unsigned)d);
        float uT = __shfl_up(vT, (unsigned)d);
        if (h >= d) { vS += uS; vT += uT; }
    }
    const float b2v = B2[f * E_ + e];
    float* row = tbl + ((size_t)f * NROW + (h + 1)) * GRS;  // interval k = h+1
    row[e]      = bS + vS;
    row[E_ + e] = bT + vT + b2v;
    if (h == 0) {
        float* r0 = tbl + (size_t)f * NROW * GRS;           // interval 0
        r0[e]      = bS;
        r0[E_ + e] = bT + b2v;
    }
}

// ---------------- main kernel: terminal stores + 2 diagnostic dup streams ----------------
// el = tid&3 (e-quartet), fq = tid>>2 (0..63): thread owns features fq and fq+64.
// Per row, stores at orow + tid*16B and orow + 4096 + tid*16B (dense 1KB per wave).
// dup1/dup2 != nullptr => each store also lands there (3x write volume total).
__global__ __launch_bounds__(THREADS, 4) void embed_main(
    const float* __restrict__ x, const float* __restrict__ tbl,
    const float* __restrict__ bps, float* __restrict__ out,
    float* __restrict__ dup1, float* __restrict__ dup2)
{
    const int tid = threadIdx.x;
    const int el  = tid & 3;
    const int fq  = tid >> 2;
    const int fA  = fq;
    const int fB  = fq + 64;
    const int r0  = blockIdx.x * RPB;

    // ---- phase 0a: x loads (one 64B line per wave-load) ----
    float xa[RPB], xb[RPB];
    #pragma unroll
    for (int i = 0; i < RPB; ++i) {
        xa[i] = x[(size_t)(r0 + i) * F_ + fA];
        xb[i] = x[(size_t)(r0 + i) * F_ + fB];
    }

    // this lane's quarter (16) of each feature's 64 sorted breakpoints (dies after digitize)
    float4 bpA[4], bpB[4];
    #pragma unroll
    for (int i = 0; i < 4; ++i) {
        bpA[i] = *(const float4*)(bps + (size_t)fA * H_ + el * 16 + 4 * i);
        bpB[i] = *(const float4*)(bps + (size_t)fB * H_ + el * 16 + 4 * i);
    }

    // ---- phase 0b: digitize all rows (pure VALU; order-independent count) ----
    int ca[RPB], cb[RPB];
    #pragma unroll
    for (int i = 0; i < RPB; ++i) {
        int a = 0, b = 0;
        #pragma unroll
        for (int j = 0; j < 4; ++j) {
            a += (bpA[j].x <= xa[i]) ? 1 : 0;
            a += (bpA[j].y <= xa[i]) ? 1 : 0;
            a += (bpA[j].z <= xa[i]) ? 1 : 0;
            a += (bpA[j].w <= xa[i]) ? 1 : 0;
            b += (bpB[j].x <= xb[i]) ? 1 : 0;
            b += (bpB[j].y <= xb[i]) ? 1 : 0;
            b += (bpB[j].z <= xb[i]) ? 1 : 0;
            b += (bpB[j].w <= xb[i]) ? 1 : 0;
        }
        // combine across the 4 el-lanes (lane bits 0-1; they share f and x)
        a += __shfl_xor(a, 1);  b += __shfl_xor(b, 1);
        a += __shfl_xor(a, 2);  b += __shfl_xor(b, 2);
        ca[i] = a; cb[i] = b;
    }

    // ---- phase 1: issue ALL table loads together ----
    const float* tA = tbl + (size_t)fA * NROW * GRS;
    const float* tB = tbl + (size_t)fB * NROW * GRS;
    float4 SA[RPB], TA[RPB], SB[RPB], TB[RPB];
    #pragma unroll
    for (int i = 0; i < RPB; ++i) {
        const float* rowA = tA + (size_t)ca[i] * GRS + el * 4;
        const float* rowB = tB + (size_t)cb[i] * GRS + el * 4;
        SA[i] = *(const float4*)(rowA);
        TA[i] = *(const float4*)(rowA + E_);
        SB[i] = *(const float4*)(rowB);
        TB[i] = *(const float4*)(rowB + E_);
    }

    // ---- phase 2: FMA + terminal stores (+ diagnostic dup streams) ----
    #pragma unroll
    for (int i = 0; i < RPB; ++i) {
        vf4 oA, oB;
        oA.x = fmaf(SA[i].x, xa[i], TA[i].x);
        oA.y = fmaf(SA[i].y, xa[i], TA[i].y);
        oA.z = fmaf(SA[i].z, xa[i], TA[i].z);
        oA.w = fmaf(SA[i].w, xa[i], TA[i].w);
        oB.x = fmaf(SB[i].x, xb[i], TB[i].x);
        oB.y = fmaf(SB[i].y, xb[i], TB[i].y);
        oB.z = fmaf(SB[i].z, xb[i], TB[i].z);
        oB.w = fmaf(SB[i].w, xb[i], TB[i].w);
        const size_t rowoff = (size_t)(r0 + i) * (F_ * E_);
        float* orow = out + rowoff;
        *(vf4*)(orow + tid * 4)        = oA;   // bytes [tid*16, +16) of row
        *(vf4*)(orow + 1024 + tid * 4) = oB;   // bytes [4096 + tid*16, +16)
        if (dup1) {                             // uniform branch; +1x write volume
            float* drow = dup1 + rowoff;
            *(vf4*)(drow + tid * 4)        = oA;
            *(vf4*)(drow + 1024 + tid * 4) = oB;
        }
        if (dup2) {                             // uniform branch; +1x write volume
            float* drow = dup2 + rowoff;
            *(vf4*)(drow + tid * 4)        = oA;
            *(vf4*)(drow + 1024 + tid * 4) = oB;
        }
    }
}

extern "C" void kernel_launch(void* const* d_in, const int* in_sizes, int n_in,
                              void* d_out, int out_size, void* d_ws, size_t ws_size,
                              hipStream_t stream) {
    const float* x  = (const float*)d_in[0];
    const float* W1 = (const float*)d_in[1];
    const float* b1 = (const float*)d_in[2];
    const float* W2 = (const float*)d_in[3];
    const float* b2 = (const float*)d_in[4];
    float* out = (float*)d_out;
    const int B = in_sizes[0] / F_;     // 16384

    // workspace: table 128*65*32 floats (1.02 MB) + sorted breakpoints (32 KB)
    float* tbl = (float*)d_ws;
    float* bps = tbl + (size_t)F_ * NROW * GRS;

    // diagnostic duplicate-write regions (3x total write volume -> forces the embed
    // dispatch above the ~84us fills and into the profiled top-5). Guarded by ws_size;
    // harness fill WRITE_SIZE=512MiB implies ws >= 512MiB. outbytes = 134.2MB.
    const size_t outbytes = (size_t)B * F_ * E_ * 4;
    const size_t off1 = (size_t)192 << 20;   // +192MiB
    const size_t off2 = (size_t)336 << 20;   // +336MiB (336MiB+134MB=470MB <= 512MiB)
    float* dup1 = (ws_size >= off1 + outbytes) ? (float*)((char*)d_ws + off1) : nullptr;
    float* dup2 = (ws_size >= off2 + outbytes) ? (float*)((char*)d_ws + off2) : nullptr;

    build_tables<<<dim3(F_, E_), 64, 0, stream>>>(W1, b1, W2, b2, tbl, bps);
    embed_main<<<B / RPB, THREADS, 0, stream>>>(x, tbl, bps, out, dup1, dup2);  // 4096 blocks
}

// Round 18
// 170.608 us; speedup vs baseline: 1.3450x; 1.3450x over previous
//
#include <hip/hip_runtime.h>

// DenseFeatureNumericEmbedding: out[b, f*16+e] = sum_h relu(x[b,f]*W1[f,h]+b1[f,h])*W2[f,e,h] + b2[f,e]
// Piecewise-linear reformulation: per (f,e) the map x->emb is piecewise linear with
// breakpoints t_h = -b1/W1; tables hold slope/intercept per (f, interval, e).
//
// Ledger: R5a build (f,e)-parallel [-28us CONFIRMED]. R16 diagnostic (3x write volume,
// embed profiled directly): WRITE exactly 3x134MB (no store amp), FETCH 17.4MB = x +
// tables-per-XCD (no read amp), VALUBusy 9.5%, bank-conflicts 0, Occupancy 50.4% =
// EXACTLY the launch_bounds(256,4) figure despite VGPR=40 allowing 8 blocks/CU.
// Marginal write BW (R13 1x=180 vs R16 3x=229 totals) ~5.4TB/s = near fill rate;
// fixed ~30us component independent of write volume. Harness-in-window = 122us.
// => The write path was never broken. The gap is the fixed ~30us of x/table load
// LATENCY that doesn't overlap the store drain at 16 waves/CU.
// R17 (single variable vs R9-best=165.5us): launch_bounds (256,4) -> (256,8).
// hipcc plausibly emits waves-per-eu min=max, pinning residency at the declared 4
// blocks/CU (the 50.4% smoking gun). 8 blocks/CU doubles latency-hiding TLP; VGPR
// 40-56 << 64 cap so no spill risk. Everything else identical to R9.
// R18/R19: identical resubmits (GPU acquisition timeouts; R17 never measured).

#define F_   128
#define H_   64
#define E_   16
#define NROW 65            // intervals 0..64
#define GRS  32            // table row stride in floats (16 S + 16 T)
#define FPB  4             // features per block
#define RPI  16            // batch rows per iteration (256 threads / 16 lanes-per-row)
#define ITERS 8
#define BPB  (RPI * ITERS) // 128 batch rows per block
#define THREADS 256

typedef float vf4 __attribute__((ext_vector_type(4)));

// ---------------- build kernel: one wave per (feature, e) ----------------
__global__ __launch_bounds__(64) void build_tables(
    const float* __restrict__ W1, const float* __restrict__ B1,
    const float* __restrict__ W2, const float* __restrict__ B2,
    float* __restrict__ tbl, float* __restrict__ bps)
{
    const int f = blockIdx.x;   // 0..127
    const int e = blockIdx.y;   // 0..15
    const int h = threadIdx.x;  // 0..63

    __shared__ float ts_raw[H_];
    __shared__ float ts_sorted[H_];
    __shared__ float scS[H_];
    __shared__ float scT[H_];

    const float w1 = W1[f * H_ + h];
    const float bb = B1[f * H_ + h];
    const bool  slope = (w1 != 0.0f);
    const float t   = slope ? (-bb / w1) : __builtin_inff();
    const float sgn = slope ? (w1 > 0.0f ? 1.0f : -1.0f) : 0.0f;
    // active as x -> -inf: W1<0 terms (x*W1 -> +inf), plus constant-on terms (W1==0, b1>0)
    const bool act0 = (w1 < 0.0f) || (!slope && bb > 0.0f);

    ts_raw[h] = t;
    __syncthreads();
    int rank = 0;
    #pragma unroll
    for (int j = 0; j < H_; ++j) {
        float tj = ts_raw[j];
        rank += (tj < t || (tj == t && j < h)) ? 1 : 0;  // tie-break by index -> permutation
    }
    ts_sorted[rank] = t;
    __syncthreads();
    if (e == 0) bps[f * H_ + h] = ts_sorted[h];

    const float w2 = W2[(f * E_ + e) * H_ + h];
    // crossing t_h upward: W1>0 -> term turns ON (+), W1<0 -> OFF (-)
    const float dS = sgn * w1 * w2;
    const float dT = sgn * bb * w2;
    float bS = act0 ? w1 * w2 : 0.0f;
    float bT = act0 ? bb * w2 : 0.0f;
    #pragma unroll
    for (int d = 32; d; d >>= 1) { bS += __shfl_xor(bS, d); bT += __shfl_xor(bT, d); }

    scS[rank] = dS; scT[rank] = dT;  // scatter deltas into sorted order
    __syncthreads();
    float vS = scS[h], vT = scT[h];
    #pragma unroll
    for (int d = 1; d < 64; d <<= 1) {   // inclusive scan over sorted positions
        float uS = __shfl_up(vS, (unsigned)d);
        float uT = __shfl_up(vT, (unsigned)d);
        if (h >= d) { vS += uS; vT += uT; }
    }
    const float b2v = B2[f * E_ + e];
    float* row = tbl + ((size_t)f * NROW + (h + 1)) * GRS;  // interval k = h+1
    row[e]      = bS + vS;
    row[E_ + e] = bT + vT + b2v;
    if (h == 0) {
        float* r0 = tbl + (size_t)f * NROW * GRS;           // interval 0
        r0[e]      = bS;
        r0[E_ + e] = bT + b2v;
    }
}

// ---------------- main kernel (no LDS) ----------------
// lane map: eq = tid&3 (e-quartet), fl = (tid>>2)&3 (feature of 4), rloc = tid>>4 (0..15)
// store addr = out + b*2048 + (f0+fl)*16 + eq*4  -> lanes 0..15 cover 256B contiguous.
// R17: __launch_bounds__(256,8) -> 8 blocks/CU (32 waves, 100%) for latency hiding.
__global__ __launch_bounds__(THREADS, 8) void embed_main(
    const float* __restrict__ x, const float* __restrict__ tbl,
    const float* __restrict__ bps, float* __restrict__ out)
{
    const int tid = threadIdx.x;
    const int f0  = blockIdx.x * FPB;

    const int   eq   = tid & 3;
    const int   fl   = (tid >> 2) & 3;
    const int   rloc = tid >> 4;          // 0..15
    const int   f    = f0 + fl;
    const int bbase  = blockIdx.y * BPB;

    // x gather, issued first (eq-lanes share the address -> one merged request)
    float xs[ITERS];
    #pragma unroll
    for (int it = 0; it < ITERS; ++it)
        xs[it] = x[(size_t)(bbase + it * RPI + rloc) * F_ + f];

    // this lane's 16 of the 64 sorted breakpoints (digitize split across eq-lanes)
    float4 bp[4];
    #pragma unroll
    for (int i = 0; i < 4; ++i)
        bp[i] = *(const float4*)(bps + (size_t)f * H_ + eq * 16 + 4 * i);

    const float* ftbl = tbl + (size_t)f * NROW * GRS;

    #pragma unroll
    for (int it = 0; it < ITERS; ++it) {
        const int   b  = bbase + it * RPI + rloc;
        const float xv = xs[it];
        // partial count of breakpoints <= xv (16 per eq-lane), pure VALU
        int c = 0;
        #pragma unroll
        for (int i = 0; i < 4; ++i) {
            c += (bp[i].x <= xv) ? 1 : 0;
            c += (bp[i].y <= xv) ? 1 : 0;
            c += (bp[i].z <= xv) ? 1 : 0;
            c += (bp[i].w <= xv) ? 1 : 0;
        }
        // combine across the 4 eq-lanes (they share xv): k in [0,64], same in all 4
        c += __shfl_xor(c, 1);
        c += __shfl_xor(c, 2);
        // direct L2 read of the interval row: eq-lanes cover full 64B lines
        const float* row = ftbl + (size_t)c * GRS + eq * 4;
        float4 S = *(const float4*)(row);
        float4 T = *(const float4*)(row + E_);
        vf4 o;
        o.x = fmaf(S.x, xv, T.x);
        o.y = fmaf(S.y, xv, T.y);
        o.z = fmaf(S.z, xv, T.z);
        o.w = fmaf(S.w, xv, T.w);
        vf4* op = (vf4*)(out + (size_t)b * (F_ * E_) + f * E_ + eq * 4);
        *op = o;
    }
}

extern "C" void kernel_launch(void* const* d_in, const int* in_sizes, int n_in,
                              void* d_out, int out_size, void* d_ws, size_t ws_size,
                              hipStream_t stream) {
    const float* x  = (const float*)d_in[0];
    const float* W1 = (const float*)d_in[1];
    const float* b1 = (const float*)d_in[2];
    const float* W2 = (const float*)d_in[3];
    const float* b2 = (const float*)d_in[4];
    float* out = (float*)d_out;
    const int B = in_sizes[0] / F_;     // 16384

    // workspace: table 128*65*32 floats (1.02 MB) + sorted breakpoints (32 KB)
    float* tbl = (float*)d_ws;
    float* bps = tbl + (size_t)F_ * NROW * GRS;

    build_tables<<<dim3(F_, E_), 64, 0, stream>>>(W1, b1, W2, b2, tbl, bps);
    dim3 grid(F_ / FPB, B / BPB);       // (32, 128)
    embed_main<<<grid, THREADS, 0, stream>>>(x, tbl, bps, out);
}